// Round 6
// baseline (637.693 us; speedup 1.0000x reference)
//
#include <hip/hip_runtime.h>
#include <hip/hip_bf16.h>
#include <hip/hip_fp16.h>

// Problem constants (match reference)
#define TT 64
#define GN 1024
#define DK 128
#define NN (TT * GN)      // 65536
#define OUTC 131          // 3 + 128
#define TAU 8e-3f         // rescue threshold, 14 sigma of fp16-induced sim error

typedef _Float16 f16x8 __attribute__((ext_vector_type(8)));
typedef float    f32x4 __attribute__((ext_vector_type(4)));

// fp32 -> fp16 round-to-nearest-even, as raw 16 bits
__device__ __forceinline__ unsigned f2h(float f) {
    return (unsigned)__half_as_ushort(__float2half(f));
}

// ---------------------------------------------------------------------------
// Kernel 1: fused fp16 conversion + per-row reciprocal norms (fp64 accum).
// ---------------------------------------------------------------------------
__global__ void kconv(const float* __restrict__ feat, unsigned* __restrict__ fh,
                      float* __restrict__ rnf, double* __restrict__ rnd) {
    int row  = blockIdx.x * 4 + (threadIdx.x >> 6);
    int lane = threadIdx.x & 63;
    const float* fr = feat + (size_t)row * DK;
    float2 v = *(const float2*)(fr + lane * 2);
    fh[(size_t)row * 64 + lane] = f2h(v.x) | (f2h(v.y) << 16);
    double s = (double)v.x * (double)v.x + (double)v.y * (double)v.y;
    #pragma unroll
    for (int off = 32; off > 0; off >>= 1)
        s += __shfl_down(s, off);
    if (lane == 0) {
        double m = sqrt(s);
        if (m < 1e-6) m = 1e-6;
        double r = 1.0 / m;
        rnd[row] = r;
        rnf[row] = (float)r;
    }
}

// ---------------------------------------------------------------------------
// Kernel 2: best-cosine-match graph, all-register fp16 MFMA, no LDS tiles,
// no barriers in the main loop. Block = 4 waves, owns 64 A-rows of group t;
// wave w owns rows w*16..w*16+15 x all 1024 B cols. B frags loaded directly
// from global (L2-hot via XCD swizzle: same t -> same XCD). Per-lane top-2
// + shfl_xor butterfly merge; fp64 rescue for gap < TAU (exact R1-R5 path).
// ---------------------------------------------------------------------------
__global__ __launch_bounds__(256) void ksim(const float* __restrict__ feat,
                                            const unsigned* __restrict__ fh,
                                            const float* __restrict__ rnf,
                                            const double* __restrict__ rnd,
                                            int* __restrict__ nxt) {
    __shared__ int nflag;
    __shared__ int lst[64];

    int id = blockIdx.x;
    int t  = (id & 7) + 8 * ((id >> 3) & 7);   // same t -> same XCD (id%8)
    int gt = id >> 6;                          // 0..15
    if (t >= TT - 1) return;                   // 16 idle blocks (t==63)
    if (threadIdx.x == 0) nflag = 0;

    int tid  = threadIdx.x;
    int wave = tid >> 6;
    int lane = tid & 63;
    int la = lane & 15;                        // fragment row/col within 16-tile
    int lq = lane >> 4;                        // quad (k slice)

    // row-major fp16 rows = 64 ints each
    const int* Ah = (const int*)fh + (size_t)(t * GN + gt * 64 + wave * 16) * 64;
    const int* Bh = (const int*)fh + (size_t)(t + 1) * GN * 64;
    const float* rB = rnf + (size_t)(t + 1) * GN;

    // A fragments: lane la -> A row la of wave tile; k = lq*8 + kc*32 halves
    f16x8 af[4];
    {
        const int* Ar = Ah + la * 64 + lq * 4;
        #pragma unroll
        for (int kc = 0; kc < 4; ++kc)
            af[kc] = __builtin_bit_cast(f16x8, *(const int4*)(Ar + kc * 16));
    }

    float t1[4], t2[4]; int i1[4];
    #pragma unroll
    for (int r = 0; r < 4; ++r) { t1[r] = -3.4e38f; t2[r] = -3.4e38f; i1[r] = 0x7fffffff; }

    const int* Bl = Bh + la * 64 + lq * 4;     // advances 16 rows (=1024 ints) per chunk
    #pragma unroll 2
    for (int c = 0; c < 64; ++c) {
        int4 b0 = *(const int4*)(Bl + 0);
        int4 b1 = *(const int4*)(Bl + 16);
        int4 b2 = *(const int4*)(Bl + 32);
        int4 b3 = *(const int4*)(Bl + 48);
        float rn = rB[c * 16 + la];
        Bl += 16 * 64;

        f32x4 acc = (f32x4){0.f, 0.f, 0.f, 0.f};
        acc = __builtin_amdgcn_mfma_f32_16x16x32_f16(af[0], __builtin_bit_cast(f16x8, b0), acc, 0, 0, 0);
        acc = __builtin_amdgcn_mfma_f32_16x16x32_f16(af[1], __builtin_bit_cast(f16x8, b1), acc, 0, 0, 0);
        acc = __builtin_amdgcn_mfma_f32_16x16x32_f16(af[2], __builtin_bit_cast(f16x8, b2), acc, 0, 0, 0);
        acc = __builtin_amdgcn_mfma_f32_16x16x32_f16(af[3], __builtin_bit_cast(f16x8, b3), acc, 0, 0, 0);

        int ncol = c * 16 + la;                // ascending per lane -> first-max tie rule
        #pragma unroll
        for (int r = 0; r < 4; ++r) {
            float v = acc[r] * rn;
            t2[r] = fmaxf(t2[r], fminf(v, t1[r]));   // med3(v, t1, t2)
            if (v > t1[r]) { t1[r] = v; i1[r] = ncol; }
        }
    }

    // ---- butterfly top-2 merge across the 16 la-lanes (same lq group) ----
    #pragma unroll
    for (int m = 1; m <= 8; m <<= 1) {
        #pragma unroll
        for (int r = 0; r < 4; ++r) {
            float o1 = __shfl_xor(t1[r], m);
            float o2 = __shfl_xor(t2[r], m);
            int   oi = __shfl_xor(i1[r], m);
            bool take = (o1 > t1[r]) || (o1 == t1[r] && oi < i1[r]);
            float nt2 = take ? fmaxf(o2, t1[r]) : fmaxf(t2[r], o1);
            if (take) { t1[r] = o1; i1[r] = oi; }
            t2[r] = nt2;
        }
    }

    __syncthreads();                           // nflag=0 visible
    if (la == 0) {
        #pragma unroll
        for (int r = 0; r < 4; ++r) {
            int row = wave * 16 + lq * 4 + r;  // 0..63 within block
            if (t1[r] - t2[r] < TAU) {
                int p = atomicAdd(&nflag, 1);
                lst[p] = row;                  // fp64 rescue
            } else {
                nxt[t * GN + gt * 64 + row] = (t + 1) * GN + i1[r];
            }
        }
    }
    __syncthreads();

    // ---- fp64 rescue, wave-parallel (exact: matches rounds 1-5 fp64 path) ----
    int nf = nflag;
    const float* Bf = feat + (size_t)(t + 1) * GN * DK;
    for (int fi = wave; fi < nf; fi += 4) {
        int r = lst[fi];
        const float* Arow = feat + (size_t)(t * GN + gt * 64 + r) * DK;
        double bv = -1e300; int bi2 = 0x7fffffff;
        for (int hh = 0; hh < 16; ++hh) {
            int h = hh * 64 + lane;
            const float* Brow = Bf + (size_t)h * DK;
            double s = 0.0;
            #pragma unroll 8
            for (int k = 0; k < DK; k += 4) {
                float4 a = *(const float4*)(Arow + k);
                float4 b = *(const float4*)(Brow + k);
                s = fma((double)a.x, (double)b.x, s);
                s = fma((double)a.y, (double)b.y, s);
                s = fma((double)a.z, (double)b.z, s);
                s = fma((double)a.w, (double)b.w, s);
            }
            s *= rnd[(t + 1) * GN + h];
            if (s > bv || (s == bv && h < bi2)) { bv = s; bi2 = h; }
        }
        #pragma unroll
        for (int off = 32; off > 0; off >>= 1) {
            double ov = __shfl_down(bv, off);
            int    oi = __shfl_down(bi2, off);
            if (ov > bv || (ov == bv && oi < bi2)) { bv = ov; bi2 = oi; }
        }
        if (lane == 0) nxt[t * GN + gt * 64 + r] = (t + 1) * GN + bi2;
    }
}

// ---------------------------------------------------------------------------
// Kernel 3: chain propagation + lengths + kept-offset scan, one block.
// Packed winner word = (chain_priority << 7) | length; double-buffered.
// ---------------------------------------------------------------------------
__global__ void kgraph(const int* __restrict__ nxt, int* __restrict__ chain_of,
                       int* __restrict__ clen, const int* __restrict__ minp,
                       int* __restrict__ offset) {
    __shared__ int winner[2 * GN];
    __shared__ int psum[1024];
    int g = threadIdx.x;            // 0..1023
    int mychain = g, mylen = 1;     // group 0: every node starts a chain
    chain_of[g] = g;
    winner[g] = 0x7fffffff;         // buffer 0 init
    int nxt_cur = nxt[g];           // prefetch t=0
    __syncthreads();
    for (int t = 0; t < TT - 1; ++t) {
        int* Wa = winner + (t & 1) * GN;
        int* Wb = winner + ((t + 1) & 1) * GN;
        int j = nxt_cur - (t + 1) * GN;         // target slot in next group
        if (t + 1 < TT - 1) nxt_cur = nxt[(t + 1) * GN + g];   // prefetch
        atomicMin(&Wa[j], (mychain << 7) | mylen);
        Wb[g] = 0x7fffffff;                     // prep next buffer
        __syncthreads();
        int w  = Wa[g];
        int wj = Wa[j];
        if ((wj >> 7) != mychain) clen[mychain] = mylen;   // chain dies here
        int node = (t + 1) * GN + g;
        if (w == 0x7fffffff) { mychain = node; mylen = 1; }
        else                 { mychain = w >> 7; mylen = (w & 127) + 1; }
        chain_of[node] = mychain;
        __syncthreads();            // Wa reads done before t+2 resets it
    }
    clen[mychain] = mylen;          // surviving chains end at group 63
    __syncthreads();

    // exclusive prefix sum of kept chain lengths over start indices
    int ml = *minp;
    int base = g * 64;
    int local = 0;
    for (int e = 0; e < 64; ++e) {
        int s = base + e;
        if (chain_of[s] == s) { int cl = clen[s]; if (cl >= ml) local += cl; }
    }
    psum[g] = local;
    __syncthreads();
    for (int off = 1; off < 1024; off <<= 1) {
        int add = (g >= off) ? psum[g - off] : 0;
        __syncthreads();
        psum[g] += add;
        __syncthreads();
    }
    int run = g ? psum[g - 1] : 0;
    for (int e = 0; e < 64; ++e) {
        int s = base + e;
        int v = 0;
        if (chain_of[s] == s) { int cl = clen[s]; if (cl >= ml) v = cl; }
        offset[s] = run;
        run += v;
    }
}

// ---------------------------------------------------------------------------
// Kernel 4: scatter kept rows, one wave per node (4 nodes / 256-thr block).
// ---------------------------------------------------------------------------
__global__ void kscatter(const float* __restrict__ coor, const float* __restrict__ feat,
                         const int* __restrict__ chain_of, const int* __restrict__ clen,
                         const int* __restrict__ offset, const int* __restrict__ minp,
                         float* __restrict__ out) {
    int node = blockIdx.x * 4 + (threadIdx.x >> 6);
    int lane = threadIdx.x & 63;
    int s = chain_of[node];
    if (clen[s] < *minp) return;
    int row = offset[s] + (node >> 10) - (s >> 10);
    float* orow = out + (size_t)row * OUTC;
    const float* f = feat + (size_t)node * DK;
    if (lane < 3) orow[lane] = coor[(size_t)node * 3 + lane];
    orow[3 + lane]  = f[lane];
    orow[67 + lane] = f[64 + lane];
}

// ---------------------------------------------------------------------------
extern "C" void kernel_launch(void* const* d_in, const int* in_sizes, int n_in,
                              void* d_out, int out_size, void* d_ws, size_t ws_size,
                              hipStream_t stream) {
    const float* coor   = (const float*)d_in[0];   // [N,3]
    const float* feat   = (const float*)d_in[1];   // [N,128]
    const int*   minlen = (const int*)d_in[2];     // scalar
    float*       out    = (float*)d_out;           // [N,131] fp32

    char* ws = (char*)d_ws;
    double*   rnd      = (double*)(ws);                            // N doubles
    float*    rnf      = (float*)(ws + (size_t)NN * 8);            // N floats
    int*      nxt      = (int*)(ws + (size_t)NN * 12);
    int*      chain_of = (int*)(ws + (size_t)NN * 16);
    int*      clen     = (int*)(ws + (size_t)NN * 20);
    int*      offset   = (int*)(ws + (size_t)NN * 24);
    unsigned* fh       = (unsigned*)(ws + (size_t)NN * 28);        // N*128 fp16 = 16 MB

    hipMemsetAsync(d_out, 0, (size_t)out_size * sizeof(float), stream);

    kconv<<<NN / 4, 256, 0, stream>>>(feat, fh, rnf, rnd);

    ksim<<<1024, 256, 0, stream>>>(feat, fh, rnf, rnd, nxt);

    kgraph<<<1, GN, 0, stream>>>(nxt, chain_of, clen, minlen, offset);
    kscatter<<<NN / 4, 256, 0, stream>>>(coor, feat, chain_of, clen, offset, minlen, out);
}